// Round 4
// baseline (78.540 us; speedup 1.0000x reference)
//
#include <hip/hip_runtime.h>

// GaussianKDE via f16 MFMA, double-buffered global_load_lds pipeline.
// estimate[q] = (norm/N) * exp2(cf2_q) * sum_n exp2( dot2(q,n) + cx2_n )
//   dot2 = sum_k (log2e * f_qk) * x_nk   (f16 MFMA, fp32 accum)
//   cf2  = -0.5*log2e*||f_q||^2 (fp32), cx2 = -0.5*log2e*||x_n||^2 (fp32)
// xh is pre-converted f16 and PRE-SWIZZLED in global (chunk c -> c^(n&7)) so a
// linear global_load_lds copy yields the swizzled LDS layout the b-frag reads
// expect (0 bank conflicts measured). BQ=128 -> 2048 blocks = 8 blocks/CU.

#define QCNT 4096
#define NCNT 50000
#define DDIM 64

// fast path
#define SPLITS 64
#define NPB 832             // 13*64; SPLITS*NPB = 53248 >= 50000 (padded)
#define NROWS (SPLITS * NPB)
#define NITERS 13
#define BQ 128
#define BN 64
#define QTILES (QCNT / BQ)  // 32

// fallback (round-2 proven path)
#define FSPLITS 32
#define FNPB 1563
#define FNITERS 25

typedef _Float16 half8_t __attribute__((ext_vector_type(8)));
typedef float float4_t __attribute__((ext_vector_type(4)));

#define K2F 1.44269504088896340f   // log2(e)
#define KC2 -0.72134752044448169f  // -0.5*log2(e)

typedef const __attribute__((address_space(1))) unsigned int* gas_u32;
typedef __attribute__((address_space(3))) unsigned int* las_u32;

__device__ __forceinline__ void gl16(const _Float16* g, _Float16* l) {
    // dest = wave-uniform LDS base + lane*16; src is per-lane
    __builtin_amdgcn_global_load_lds((gas_u32)(const void*)g, (las_u32)(void*)l,
                                     16, 0, 0);
}

// ---- fused prep: blocks [0,1024) do f-prep; [1024, 2688) do x-prep ------
#define PREP_F_BLOCKS (QCNT / 4)            // 1024
#define PREP_X_BLOCKS (NROWS * 8 / 256)     // 1664

__global__ void prep_fused(const float* __restrict__ features,
                           const float* __restrict__ bw,
                           const float* __restrict__ dataset,
                           _Float16* __restrict__ fh,
                           float* __restrict__ cf2,
                           _Float16* __restrict__ xh,
                           float* __restrict__ cx2g) {
    if (blockIdx.x < PREP_F_BLOCKS) {
        // f = features@bw; fh = f16(K2*f); cf2 = KC2*||f||^2  (1 wave / q-row)
        const int lane = threadIdx.x & 63;
        const int q = blockIdx.x * 4 + (threadIdx.x >> 6);
        const float* frow = features + q * DDIM;
        float acc = 0.f;
#pragma unroll
        for (int k = 0; k < DDIM; ++k)
            acc = fmaf(frow[k], bw[k * DDIM + lane], acc);
        fh[(size_t)q * DDIM + lane] = (_Float16)(K2F * acc);
        float s = acc * acc;
#pragma unroll
        for (int m = 1; m < 64; m <<= 1) s += __shfl_xor(s, m, 64);
        if (lane == 0) cf2[q] = KC2 * s;
    } else {
        // xh = swizzled f16 dataset (padded); cx2g = KC2*||x||^2
        const int t = (blockIdx.x - PREP_F_BLOCKS) * 256 + threadIdx.x;
        const int row = t >> 3;
        const int c = t & 7;                  // 8-float chunk
        if (row >= NROWS) return;
        float4_t v0 = {0.f, 0.f, 0.f, 0.f}, v1 = {0.f, 0.f, 0.f, 0.f};
        if (row < NCNT) {
            const float4_t* src = (const float4_t*)(dataset + (size_t)row * DDIM + c * 8);
            v0 = src[0]; v1 = src[1];
        }
        float s = v0[0]*v0[0] + v0[1]*v0[1] + v0[2]*v0[2] + v0[3]*v0[3]
                + v1[0]*v1[0] + v1[1]*v1[1] + v1[2]*v1[2] + v1[3]*v1[3];
        s += __shfl_xor(s, 1, 64);
        s += __shfl_xor(s, 2, 64);
        s += __shfl_xor(s, 4, 64);
        if (c == 0) cx2g[row] = (row < NCNT) ? KC2 * s : -3.0e38f;
        half8_t h;
        h[0] = (_Float16)v0[0]; h[1] = (_Float16)v0[1];
        h[2] = (_Float16)v0[2]; h[3] = (_Float16)v0[3];
        h[4] = (_Float16)v1[0]; h[5] = (_Float16)v1[1];
        h[6] = (_Float16)v1[2]; h[7] = (_Float16)v1[3];
        *(half8_t*)(xh + (size_t)row * DDIM + ((c ^ (row & 7)) * 8)) = h;
    }
}

// ---- main (fast): dbuf global_load_lds pipeline, 8 blocks/CU ------------
__global__ __launch_bounds__(256, 8)
void kde_main_fast(const _Float16* __restrict__ fh,
                   const float* __restrict__ cx2g,
                   const _Float16* __restrict__ xh,
                   float* __restrict__ partial) {
    __shared__ __align__(16) _Float16 xt[2][BN * DDIM];   // 2 x 8 KB
    __shared__ float lcx2[NPB];                           // 3.25 KB

    const int tid = threadIdx.x;
    const int lane = tid & 63;
    const int w = tid >> 6;
    const int l15 = lane & 15;
    const int lh = lane >> 4;

    // bijective XCD swizzle: 2048 = 8 xcd x (8 splits x 32 qtiles)
    const int bid = blockIdx.x;
    const int xcd = bid & 7;
    const int j = bid >> 3;                 // 0..255
    const int split = xcd * 8 + (j & 7);    // 0..63
    const int qtile = j >> 3;               // 0..31

    const int qbase = qtile * BQ + w * 32;  // wave owns 32 q-rows
    const _Float16* xslice = xh + (size_t)split * NPB * DDIM;
    const float* cxs = cx2g + split * NPB;

    // A fragments resident in VGPRs: lane l -> row qt*16+l15, k = kt*32+lh*8
    half8_t a[2][2];
#pragma unroll
    for (int qt = 0; qt < 2; ++qt)
#pragma unroll
        for (int kt = 0; kt < 2; ++kt)
            a[qt][kt] = *(const half8_t*)(fh + (size_t)(qbase + qt * 16 + l15) * DDIM
                                             + kt * 32 + lh * 8);

    // persistent cx2 tile for all 13 iterations
    for (int i = tid; i < NPB; i += 256) lcx2[i] = cxs[i];

    float sum[2][4];
#pragma unroll
    for (int qt = 0; qt < 2; ++qt)
#pragma unroll
        for (int r = 0; r < 4; ++r) sum[qt][r] = 0.f;

    // stage tile `it` into buffer bsel: 2 global_load_lds_dwordx4 per wave
#define STAGE(it_, bsel_)                                                     \
    {                                                                         \
        const _Float16* gsrc_ = xslice + (size_t)(it_) * BN * DDIM;           \
        _Float16* dst_ = &xt[bsel_][0];                                       \
        _Pragma("unroll")                                                     \
        for (int jj = 0; jj < 2; ++jj) {                                      \
            const int ci = w * 128 + jj * 64 + lane;                          \
            gl16(gsrc_ + ci * 8, dst_ + (w * 128 + jj * 64) * 8);             \
        }                                                                     \
    }

    STAGE(0, 0);
    __syncthreads();   // full drain once: lcx2 writes + tile-0 loads

    int cur = 0;
    for (int it = 0; it < NITERS; ++it) {
        if (it + 1 < NITERS) STAGE(it + 1, cur ^ 1);   // prefetch next tile
        const _Float16* xb = &xt[cur][0];
#pragma unroll
        for (int nt = 0; nt < 4; ++nt) {
            const int brow = nt * 16 + l15;
            const float c2 = lcx2[it * BN + brow];     // broadcast across lh
            const half8_t b0 = *(const half8_t*)(xb + brow * DDIM + ((lh ^ (brow & 7)) * 8));
            const half8_t b1 = *(const half8_t*)(xb + brow * DDIM + (((4 + lh) ^ (brow & 7)) * 8));
#pragma unroll
            for (int qt = 0; qt < 2; ++qt) {
                float4_t c = {c2, c2, c2, c2};         // fold cx2 into C-input
                float4_t acc = __builtin_amdgcn_mfma_f32_16x16x32_f16(a[qt][0], b0, c, 0, 0, 0);
                acc = __builtin_amdgcn_mfma_f32_16x16x32_f16(a[qt][1], b1, acc, 0, 0, 0);
#pragma unroll
                for (int r = 0; r < 4; ++r)
                    sum[qt][r] += __builtin_amdgcn_exp2f(acc[r]);
            }
        }
        asm volatile("s_waitcnt vmcnt(0)" ::: "memory");  // prefetch landed
        __builtin_amdgcn_s_barrier();                      // raw: no full drain
        asm volatile("" ::: "memory");
        cur ^= 1;
    }

    // reduce over the 16 n-columns
#pragma unroll
    for (int qt = 0; qt < 2; ++qt)
#pragma unroll
        for (int r = 0; r < 4; ++r) {
            float s = sum[qt][r];
            s += __shfl_xor(s, 1, 64);
            s += __shfl_xor(s, 2, 64);
            s += __shfl_xor(s, 4, 64);
            s += __shfl_xor(s, 8, 64);
            sum[qt][r] = s;
        }
    if (l15 == 0) {
        float* dst = partial + (size_t)split * QCNT + qbase;
#pragma unroll
        for (int qt = 0; qt < 2; ++qt)
#pragma unroll
            for (int r = 0; r < 4; ++r)
                dst[qt * 16 + lh * 4 + r] = sum[qt][r];   // C row = lh*4 + r
    }
#undef STAGE
}

// ======================= fallback path (round-2, proven) ==================
__global__ void prep_f_kernel(const float* __restrict__ features,
                              const float* __restrict__ bw,
                              _Float16* __restrict__ fh,
                              float* __restrict__ cf2) {
    const int lane = threadIdx.x & 63;
    const int q = blockIdx.x * (blockDim.x >> 6) + (threadIdx.x >> 6);
    if (q >= QCNT) return;
    const float* frow = features + q * DDIM;
    float acc = 0.f;
#pragma unroll
    for (int k = 0; k < DDIM; ++k)
        acc = fmaf(frow[k], bw[k * DDIM + lane], acc);
    fh[(size_t)q * DDIM + lane] = (_Float16)(K2F * acc);
    float s = acc * acc;
#pragma unroll
    for (int m = 1; m < 64; m <<= 1) s += __shfl_xor(s, m, 64);
    if (lane == 0) cf2[q] = KC2 * s;
}

__global__ void prep_x2_kernel(const float* __restrict__ dataset,
                               float* __restrict__ cx2) {
    const int n = blockIdx.x * blockDim.x + threadIdx.x;
    if (n >= NCNT) return;
    const float4* row = (const float4*)(dataset + (size_t)n * DDIM);
    float s = 0.f;
#pragma unroll
    for (int jq = 0; jq < DDIM / 4; ++jq) {
        float4 v = row[jq];
        s += v.x * v.x + v.y * v.y + v.z * v.z + v.w * v.w;
    }
    cx2[n] = KC2 * s;
}

__global__ __launch_bounds__(256, 2)
void kde_main_fb(const _Float16* __restrict__ fh,
                 const float* __restrict__ cx2,
                 const float* __restrict__ dataset,
                 float* __restrict__ partial) {
    __shared__ __align__(16) _Float16 xt[BN * DDIM];
    const int tid = threadIdx.x;
    const int lane = tid & 63;
    const int w = tid >> 6;
    const int l15 = lane & 15;
    const int lh = lane >> 4;
    const int qbase = blockIdx.x * 256 + w * 64;
    const int nstart = blockIdx.y * FNPB;
    const int nlimit = min(nstart + FNPB, NCNT);

    half8_t a[4][2];
#pragma unroll
    for (int qt = 0; qt < 4; ++qt)
#pragma unroll
        for (int kt = 0; kt < 2; ++kt)
            a[qt][kt] = *(const half8_t*)(fh + (size_t)(qbase + qt * 16 + l15) * DDIM
                                             + kt * 32 + lh * 8);
    float sum[4][4];
#pragma unroll
    for (int qt = 0; qt < 4; ++qt)
#pragma unroll
        for (int r = 0; r < 4; ++r) sum[qt][r] = 0.f;

    const int sn = tid >> 2;
    const int sk = tid & 3;
    const int c0 = (sk * 2) ^ (sn & 7);
    const int c1 = (sk * 2 + 1) ^ (sn & 7);

    for (int it = 0; it < FNITERS; ++it) {
        const int nb = nstart + it * BN;
        __syncthreads();
        {
            const int ng = nb + sn;
            float4_t v0 = {0.f,0.f,0.f,0.f}, v1 = {0.f,0.f,0.f,0.f};
            float4_t v2 = {0.f,0.f,0.f,0.f}, v3 = {0.f,0.f,0.f,0.f};
            if (ng < nlimit) {
                const float4_t* src = (const float4_t*)(dataset + (size_t)ng * DDIM + sk * 16);
                v0 = src[0]; v1 = src[1]; v2 = src[2]; v3 = src[3];
            }
            half8_t h0, h1;
            h0[0]=(_Float16)v0[0]; h0[1]=(_Float16)v0[1]; h0[2]=(_Float16)v0[2]; h0[3]=(_Float16)v0[3];
            h0[4]=(_Float16)v1[0]; h0[5]=(_Float16)v1[1]; h0[6]=(_Float16)v1[2]; h0[7]=(_Float16)v1[3];
            h1[0]=(_Float16)v2[0]; h1[1]=(_Float16)v2[1]; h1[2]=(_Float16)v2[2]; h1[3]=(_Float16)v2[3];
            h1[4]=(_Float16)v3[0]; h1[5]=(_Float16)v3[1]; h1[6]=(_Float16)v3[2]; h1[7]=(_Float16)v3[3];
            *(half8_t*)(xt + sn * DDIM + c0 * 8) = h0;
            *(half8_t*)(xt + sn * DDIM + c1 * 8) = h1;
        }
        __syncthreads();
#pragma unroll
        for (int nt = 0; nt < 4; ++nt) {
            const int ng = nb + nt * 16 + l15;
            const float c2 = (ng < nlimit) ? cx2[ng] : -1.0e30f;
            const int brow = nt * 16 + l15;
            const half8_t b0 = *(const half8_t*)(xt + brow * DDIM + ((lh ^ (brow & 7)) * 8));
            const half8_t b1 = *(const half8_t*)(xt + brow * DDIM + (((4 + lh) ^ (brow & 7)) * 8));
#pragma unroll
            for (int qt = 0; qt < 4; ++qt) {
                float4_t c = {c2, c2, c2, c2};
                float4_t acc = __builtin_amdgcn_mfma_f32_16x16x32_f16(a[qt][0], b0, c, 0, 0, 0);
                acc = __builtin_amdgcn_mfma_f32_16x16x32_f16(a[qt][1], b1, acc, 0, 0, 0);
#pragma unroll
                for (int r = 0; r < 4; ++r)
                    sum[qt][r] += __builtin_amdgcn_exp2f(acc[r]);
            }
        }
    }
#pragma unroll
    for (int qt = 0; qt < 4; ++qt)
#pragma unroll
        for (int r = 0; r < 4; ++r) {
            float s = sum[qt][r];
            s += __shfl_xor(s, 1, 64);
            s += __shfl_xor(s, 2, 64);
            s += __shfl_xor(s, 4, 64);
            s += __shfl_xor(s, 8, 64);
            sum[qt][r] = s;
        }
    if (l15 == 0) {
        float* dst = partial + (size_t)blockIdx.y * QCNT + qbase;
#pragma unroll
        for (int qt = 0; qt < 4; ++qt)
#pragma unroll
            for (int r = 0; r < 4; ++r)
                dst[qt * 16 + lh * 4 + r] = sum[qt][r];
    }
}

// ---- final: out[q] = (sum_sp partial) * exp2(cf2[q]) * norm / N ---------
__global__ void reduce_kernel(const float* __restrict__ partial,
                              const float* __restrict__ cf2,
                              const float* __restrict__ norm,
                              float* __restrict__ out, int splits) {
    const int q = blockIdx.x * blockDim.x + threadIdx.x;
    if (q >= QCNT) return;
    float s = 0.f;
    for (int sp = 0; sp < splits; ++sp) s += partial[(size_t)sp * QCNT + q];
    out[q] = s * __builtin_amdgcn_exp2f(cf2[q]) * norm[0] * (1.0f / (float)NCNT);
}

extern "C" void kernel_launch(void* const* d_in, const int* in_sizes, int n_in,
                              void* d_out, int out_size, void* d_ws, size_t ws_size,
                              hipStream_t stream) {
    const float* features = (const float*)d_in[0];
    const float* bw       = (const float*)d_in[1];
    const float* dataset  = (const float*)d_in[2];
    const float* norm     = (const float*)d_in[3];
    float* out = (float*)d_out;
    float* ws = (float*)d_ws;

    // fast-path ws layout (floats): xh 1703936 | fh 131072 | cf2 4096 |
    // cx2g 53248 | partial 262144  => 8.62 MB
    const size_t NEED = (size_t)(1703936 + 131072 + 4096 + 53248 + 262144) * 4;

    if (ws_size >= NEED) {
        _Float16* xh = (_Float16*)ws;
        _Float16* fh = (_Float16*)(ws + 1703936);
        float* cf2     = ws + 1703936 + 131072;
        float* cx2g    = cf2 + 4096;
        float* partial = cx2g + 53248;

        prep_fused<<<PREP_F_BLOCKS + PREP_X_BLOCKS, 256, 0, stream>>>(
            features, bw, dataset, fh, cf2, xh, cx2g);
        kde_main_fast<<<QTILES * SPLITS, 256, 0, stream>>>(fh, cx2g, xh, partial);
        reduce_kernel<<<QCNT / 256, 256, 0, stream>>>(partial, cf2, norm, out, SPLITS);
    } else {
        _Float16* fh = (_Float16*)ws;                 // 131072 floats
        float* cf2     = ws + 131072;
        float* cx2     = ws + 131072 + 4096;
        float* partial = ws + 131072 + 4096 + 50176;  // FSPLITS*QCNT

        prep_f_kernel<<<QCNT / 4, 256, 0, stream>>>(features, bw, fh, cf2);
        prep_x2_kernel<<<(NCNT + 255) / 256, 256, 0, stream>>>(dataset, cx2);
        dim3 grid(QCNT / 256, FSPLITS);
        kde_main_fb<<<grid, 256, 0, stream>>>(fh, cx2, dataset, partial);
        reduce_kernel<<<QCNT / 256, 256, 0, stream>>>(partial, cf2, norm, out, FSPLITS);
    }
}

// Round 5
// 74.286 us; speedup vs baseline: 1.0573x; 1.0573x over previous
//
#include <hip/hip_runtime.h>

// GaussianKDE via f16 MFMA, 4-buffer counted-vmcnt global_load_lds pipeline.
// estimate[q] = (norm/N) * exp2(cf2_q) * sum_n exp2( dot2(q,n) + cx2_n )
//   dot2 = sum_k (log2e * f_qk) * x_nk   (f16 MFMA, fp32 accum)
//   cf2  = -0.5*log2e*||f_q||^2 (fp32), cx2 = -0.5*log2e*||x_n||^2 (fp32)
// xh is pre-converted f16 and PRE-SWIZZLED in global (chunk c -> c^(n&7)) so a
// linear global_load_lds copy yields the swizzled LDS layout the b-frag reads
// expect (0 bank conflicts measured). BQ=256 (r3 winner: amortizes b-frag
// reads over 4 q-subtiles). Depth-2 prefetch, s_waitcnt vmcnt(2) steady state
// (never 0 until the last tile) -- loads stay in flight across barriers (T4).

#define QCNT 4096
#define NCNT 50000
#define DDIM 64

// fast path
#define SPLITS 64
#define NPB 832             // 13*64; SPLITS*NPB = 53248 >= 50000 (padded)
#define NROWS (SPLITS * NPB)
#define NITERS 13
#define BQ 256
#define BN 64
#define QTILES (QCNT / BQ)  // 16

// fallback (round-2 proven path)
#define FSPLITS 32
#define FNPB 1563
#define FNITERS 25

typedef _Float16 half8_t __attribute__((ext_vector_type(8)));
typedef float float4_t __attribute__((ext_vector_type(4)));

#define K2F 1.44269504088896340f   // log2(e)
#define KC2 -0.72134752044448169f  // -0.5*log2(e)

typedef const __attribute__((address_space(1))) unsigned int* gas_u32;
typedef __attribute__((address_space(3))) unsigned int* las_u32;

__device__ __forceinline__ void gl16(const _Float16* g, _Float16* l) {
    // dest = wave-uniform LDS base + lane*16; src is per-lane
    __builtin_amdgcn_global_load_lds((gas_u32)(const void*)g, (las_u32)(void*)l,
                                     16, 0, 0);
}

// ---- fused prep: blocks [0,1024) do f-prep; [1024, 2688) do x-prep ------
#define PREP_F_BLOCKS (QCNT / 4)            // 1024
#define PREP_X_BLOCKS (NROWS * 8 / 256)     // 1664

__global__ void prep_fused(const float* __restrict__ features,
                           const float* __restrict__ bw,
                           const float* __restrict__ dataset,
                           _Float16* __restrict__ fh,
                           float* __restrict__ cf2,
                           _Float16* __restrict__ xh,
                           float* __restrict__ cx2g) {
    if (blockIdx.x < PREP_F_BLOCKS) {
        // f = features@bw; fh = f16(K2*f); cf2 = KC2*||f||^2  (1 wave / q-row)
        const int lane = threadIdx.x & 63;
        const int q = blockIdx.x * 4 + (threadIdx.x >> 6);
        const float* frow = features + q * DDIM;
        float acc = 0.f;
#pragma unroll
        for (int k = 0; k < DDIM; ++k)
            acc = fmaf(frow[k], bw[k * DDIM + lane], acc);
        fh[(size_t)q * DDIM + lane] = (_Float16)(K2F * acc);
        float s = acc * acc;
#pragma unroll
        for (int m = 1; m < 64; m <<= 1) s += __shfl_xor(s, m, 64);
        if (lane == 0) cf2[q] = KC2 * s;
    } else {
        // xh = swizzled f16 dataset (padded); cx2g = KC2*||x||^2
        const int t = (blockIdx.x - PREP_F_BLOCKS) * 256 + threadIdx.x;
        const int row = t >> 3;
        const int c = t & 7;                  // 8-float chunk
        if (row >= NROWS) return;
        float4_t v0 = {0.f, 0.f, 0.f, 0.f}, v1 = {0.f, 0.f, 0.f, 0.f};
        if (row < NCNT) {
            const float4_t* src = (const float4_t*)(dataset + (size_t)row * DDIM + c * 8);
            v0 = src[0]; v1 = src[1];
        }
        float s = v0[0]*v0[0] + v0[1]*v0[1] + v0[2]*v0[2] + v0[3]*v0[3]
                + v1[0]*v1[0] + v1[1]*v1[1] + v1[2]*v1[2] + v1[3]*v1[3];
        s += __shfl_xor(s, 1, 64);
        s += __shfl_xor(s, 2, 64);
        s += __shfl_xor(s, 4, 64);
        if (c == 0) cx2g[row] = (row < NCNT) ? KC2 * s : -3.0e38f;
        half8_t h;
        h[0] = (_Float16)v0[0]; h[1] = (_Float16)v0[1];
        h[2] = (_Float16)v0[2]; h[3] = (_Float16)v0[3];
        h[4] = (_Float16)v1[0]; h[5] = (_Float16)v1[1];
        h[6] = (_Float16)v1[2]; h[7] = (_Float16)v1[3];
        *(half8_t*)(xh + (size_t)row * DDIM + ((c ^ (row & 7)) * 8)) = h;
    }
}

// ---- main (fast): 4-buffer counted-vmcnt pipeline, 4 blocks/CU ----------
__global__ __launch_bounds__(256, 4)
void kde_main_fast(const _Float16* __restrict__ fh,
                   const float* __restrict__ cx2g,
                   const _Float16* __restrict__ xh,
                   float* __restrict__ partial) {
    __shared__ __align__(16) _Float16 xt[4][BN * DDIM];   // 4 x 8 KB
    __shared__ float lcx2[NPB];                           // 3.25 KB

    const int tid = threadIdx.x;
    const int lane = tid & 63;
    const int w = tid >> 6;
    const int l15 = lane & 15;
    const int lh = lane >> 4;

    // bijective XCD swizzle: 1024 = 8 xcd x (8 splits x 16 qtiles)
    const int bid = blockIdx.x;
    const int xcd = bid & 7;
    const int j = bid >> 3;                 // 0..127
    const int split = xcd * 8 + (j & 7);    // 0..63
    const int qtile = j >> 3;               // 0..15

    const int qbase = qtile * BQ + w * 64;  // wave owns 64 q-rows
    const _Float16* xslice = xh + (size_t)split * NPB * DDIM;
    const float* cxs = cx2g + split * NPB;

    // A fragments resident in VGPRs: lane l -> row qt*16+l15, k = kt*32+lh*8
    half8_t a[4][2];
#pragma unroll
    for (int qt = 0; qt < 4; ++qt)
#pragma unroll
        for (int kt = 0; kt < 2; ++kt)
            a[qt][kt] = *(const half8_t*)(fh + (size_t)(qbase + qt * 16 + l15) * DDIM
                                             + kt * 32 + lh * 8);

    // persistent cx2 tile for all 13 iterations
    for (int i = tid; i < NPB; i += 256) lcx2[i] = cxs[i];

    float sum[4][4];
#pragma unroll
    for (int qt = 0; qt < 4; ++qt)
#pragma unroll
        for (int r = 0; r < 4; ++r) sum[qt][r] = 0.f;

    // stage tile `it` into buffer bsel: 2 global_load_lds_dwordx4 per wave
#define STAGE(it_, bsel_)                                                     \
    {                                                                         \
        const _Float16* gsrc_ = xslice + (size_t)(it_) * BN * DDIM;           \
        _Float16* dst_ = &xt[bsel_][0];                                       \
        _Pragma("unroll")                                                     \
        for (int jj = 0; jj < 2; ++jj) {                                      \
            const int ci = w * 128 + jj * 64 + lane;                          \
            gl16(gsrc_ + ci * 8, dst_ + (w * 128 + jj * 64) * 8);             \
        }                                                                     \
    }

    // compute on tile `it` living in buffer xb_
#define COMPUTE(it_, xb_)                                                     \
    {                                                                         \
        const _Float16* xb = xb_;                                             \
        _Pragma("unroll")                                                     \
        for (int nt = 0; nt < 4; ++nt) {                                      \
            const int brow = nt * 16 + l15;                                   \
            const float c2 = lcx2[(it_) * BN + brow];                         \
            const half8_t b0 = *(const half8_t*)(xb + brow * DDIM             \
                                   + ((lh ^ (brow & 7)) * 8));                \
            const half8_t b1 = *(const half8_t*)(xb + brow * DDIM             \
                                   + (((4 + lh) ^ (brow & 7)) * 8));          \
            _Pragma("unroll")                                                 \
            for (int qt = 0; qt < 4; ++qt) {                                  \
                float4_t c = {c2, c2, c2, c2};                                \
                float4_t acc = __builtin_amdgcn_mfma_f32_16x16x32_f16(        \
                    a[qt][0], b0, c, 0, 0, 0);                                \
                acc = __builtin_amdgcn_mfma_f32_16x16x32_f16(                 \
                    a[qt][1], b1, acc, 0, 0, 0);                              \
                _Pragma("unroll")                                             \
                for (int r = 0; r < 4; ++r)                                   \
                    sum[qt][r] += __builtin_amdgcn_exp2f(acc[r]);             \
            }                                                                 \
        }                                                                     \
    }

    __syncthreads();            // lcx2 visible (one-time full drain; no stages yet)

    STAGE(0, 0);                // depth-2 prologue
    STAGE(1, 1);

    for (int it = 0; it < NITERS - 1; ++it) {
        // wait for the OLDEST stage only (tile it); tiles it+1[,it+2] stay in flight
        asm volatile("s_waitcnt vmcnt(2)" ::: "memory");
        __builtin_amdgcn_s_barrier();       // all waves' quarter-tiles of `it` landed
        asm volatile("" ::: "memory");
        if (it + 2 < NITERS) STAGE(it + 2, (it + 2) & 3);  // overwrites tile it-2: safe
        COMPUTE(it, &xt[it & 3][0]);
    }
    {   // last tile: full drain (only tile 12 is outstanding)
        asm volatile("s_waitcnt vmcnt(0)" ::: "memory");
        __builtin_amdgcn_s_barrier();
        asm volatile("" ::: "memory");
        COMPUTE(NITERS - 1, &xt[(NITERS - 1) & 3][0]);
    }

    // reduce over the 16 n-columns
#pragma unroll
    for (int qt = 0; qt < 4; ++qt)
#pragma unroll
        for (int r = 0; r < 4; ++r) {
            float s = sum[qt][r];
            s += __shfl_xor(s, 1, 64);
            s += __shfl_xor(s, 2, 64);
            s += __shfl_xor(s, 4, 64);
            s += __shfl_xor(s, 8, 64);
            sum[qt][r] = s;
        }
    if (l15 == 0) {
        float* dst = partial + (size_t)split * QCNT + qbase;
#pragma unroll
        for (int qt = 0; qt < 4; ++qt)
#pragma unroll
            for (int r = 0; r < 4; ++r)
                dst[qt * 16 + lh * 4 + r] = sum[qt][r];   // C row = lh*4 + r
    }
#undef STAGE
#undef COMPUTE
}

// ======================= fallback path (round-2, proven) ==================
__global__ void prep_f_kernel(const float* __restrict__ features,
                              const float* __restrict__ bw,
                              _Float16* __restrict__ fh,
                              float* __restrict__ cf2) {
    const int lane = threadIdx.x & 63;
    const int q = blockIdx.x * (blockDim.x >> 6) + (threadIdx.x >> 6);
    if (q >= QCNT) return;
    const float* frow = features + q * DDIM;
    float acc = 0.f;
#pragma unroll
    for (int k = 0; k < DDIM; ++k)
        acc = fmaf(frow[k], bw[k * DDIM + lane], acc);
    fh[(size_t)q * DDIM + lane] = (_Float16)(K2F * acc);
    float s = acc * acc;
#pragma unroll
    for (int m = 1; m < 64; m <<= 1) s += __shfl_xor(s, m, 64);
    if (lane == 0) cf2[q] = KC2 * s;
}

__global__ void prep_x2_kernel(const float* __restrict__ dataset,
                               float* __restrict__ cx2) {
    const int n = blockIdx.x * blockDim.x + threadIdx.x;
    if (n >= NCNT) return;
    const float4* row = (const float4*)(dataset + (size_t)n * DDIM);
    float s = 0.f;
#pragma unroll
    for (int jq = 0; jq < DDIM / 4; ++jq) {
        float4 v = row[jq];
        s += v.x * v.x + v.y * v.y + v.z * v.z + v.w * v.w;
    }
    cx2[n] = KC2 * s;
}

__global__ __launch_bounds__(256, 2)
void kde_main_fb(const _Float16* __restrict__ fh,
                 const float* __restrict__ cx2,
                 const float* __restrict__ dataset,
                 float* __restrict__ partial) {
    __shared__ __align__(16) _Float16 xt[BN * DDIM];
    const int tid = threadIdx.x;
    const int lane = tid & 63;
    const int w = tid >> 6;
    const int l15 = lane & 15;
    const int lh = lane >> 4;
    const int qbase = blockIdx.x * 256 + w * 64;
    const int nstart = blockIdx.y * FNPB;
    const int nlimit = min(nstart + FNPB, NCNT);

    half8_t a[4][2];
#pragma unroll
    for (int qt = 0; qt < 4; ++qt)
#pragma unroll
        for (int kt = 0; kt < 2; ++kt)
            a[qt][kt] = *(const half8_t*)(fh + (size_t)(qbase + qt * 16 + l15) * DDIM
                                             + kt * 32 + lh * 8);
    float sum[4][4];
#pragma unroll
    for (int qt = 0; qt < 4; ++qt)
#pragma unroll
        for (int r = 0; r < 4; ++r) sum[qt][r] = 0.f;

    const int sn = tid >> 2;
    const int sk = tid & 3;
    const int c0 = (sk * 2) ^ (sn & 7);
    const int c1 = (sk * 2 + 1) ^ (sn & 7);

    for (int it = 0; it < FNITERS; ++it) {
        const int nb = nstart + it * BN;
        __syncthreads();
        {
            const int ng = nb + sn;
            float4_t v0 = {0.f,0.f,0.f,0.f}, v1 = {0.f,0.f,0.f,0.f};
            float4_t v2 = {0.f,0.f,0.f,0.f}, v3 = {0.f,0.f,0.f,0.f};
            if (ng < nlimit) {
                const float4_t* src = (const float4_t*)(dataset + (size_t)ng * DDIM + sk * 16);
                v0 = src[0]; v1 = src[1]; v2 = src[2]; v3 = src[3];
            }
            half8_t h0, h1;
            h0[0]=(_Float16)v0[0]; h0[1]=(_Float16)v0[1]; h0[2]=(_Float16)v0[2]; h0[3]=(_Float16)v0[3];
            h0[4]=(_Float16)v1[0]; h0[5]=(_Float16)v1[1]; h0[6]=(_Float16)v1[2]; h0[7]=(_Float16)v1[3];
            h1[0]=(_Float16)v2[0]; h1[1]=(_Float16)v2[1]; h1[2]=(_Float16)v2[2]; h1[3]=(_Float16)v2[3];
            h1[4]=(_Float16)v3[0]; h1[5]=(_Float16)v3[1]; h1[6]=(_Float16)v3[2]; h1[7]=(_Float16)v3[3];
            *(half8_t*)(xt + sn * DDIM + c0 * 8) = h0;
            *(half8_t*)(xt + sn * DDIM + c1 * 8) = h1;
        }
        __syncthreads();
#pragma unroll
        for (int nt = 0; nt < 4; ++nt) {
            const int ng = nb + nt * 16 + l15;
            const float c2 = (ng < nlimit) ? cx2[ng] : -1.0e30f;
            const int brow = nt * 16 + l15;
            const half8_t b0 = *(const half8_t*)(xt + brow * DDIM + ((lh ^ (brow & 7)) * 8));
            const half8_t b1 = *(const half8_t*)(xt + brow * DDIM + (((4 + lh) ^ (brow & 7)) * 8));
#pragma unroll
            for (int qt = 0; qt < 4; ++qt) {
                float4_t c = {c2, c2, c2, c2};
                float4_t acc = __builtin_amdgcn_mfma_f32_16x16x32_f16(a[qt][0], b0, c, 0, 0, 0);
                acc = __builtin_amdgcn_mfma_f32_16x16x32_f16(a[qt][1], b1, acc, 0, 0, 0);
#pragma unroll
                for (int r = 0; r < 4; ++r)
                    sum[qt][r] += __builtin_amdgcn_exp2f(acc[r]);
            }
        }
    }
#pragma unroll
    for (int qt = 0; qt < 4; ++qt)
#pragma unroll
        for (int r = 0; r < 4; ++r) {
            float s = sum[qt][r];
            s += __shfl_xor(s, 1, 64);
            s += __shfl_xor(s, 2, 64);
            s += __shfl_xor(s, 4, 64);
            s += __shfl_xor(s, 8, 64);
            sum[qt][r] = s;
        }
    if (l15 == 0) {
        float* dst = partial + (size_t)blockIdx.y * QCNT + qbase;
#pragma unroll
        for (int qt = 0; qt < 4; ++qt)
#pragma unroll
            for (int r = 0; r < 4; ++r)
                dst[qt * 16 + lh * 4 + r] = sum[qt][r];
    }
}

// ---- final: out[q] = (sum_sp partial) * exp2(cf2[q]) * norm / N ---------
__global__ void reduce_kernel(const float* __restrict__ partial,
                              const float* __restrict__ cf2,
                              const float* __restrict__ norm,
                              float* __restrict__ out, int splits) {
    const int q = blockIdx.x * blockDim.x + threadIdx.x;
    if (q >= QCNT) return;
    float s = 0.f;
    for (int sp = 0; sp < splits; ++sp) s += partial[(size_t)sp * QCNT + q];
    out[q] = s * __builtin_amdgcn_exp2f(cf2[q]) * norm[0] * (1.0f / (float)NCNT);
}

extern "C" void kernel_launch(void* const* d_in, const int* in_sizes, int n_in,
                              void* d_out, int out_size, void* d_ws, size_t ws_size,
                              hipStream_t stream) {
    const float* features = (const float*)d_in[0];
    const float* bw       = (const float*)d_in[1];
    const float* dataset  = (const float*)d_in[2];
    const float* norm     = (const float*)d_in[3];
    float* out = (float*)d_out;
    float* ws = (float*)d_ws;

    // fast-path ws layout (floats): xh 1703936 | fh 131072 | cf2 4096 |
    // cx2g 53248 | partial 262144  => 8.62 MB
    const size_t NEED = (size_t)(1703936 + 131072 + 4096 + 53248 + 262144) * 4;

    if (ws_size >= NEED) {
        _Float16* xh = (_Float16*)ws;
        _Float16* fh = (_Float16*)(ws + 1703936);
        float* cf2     = ws + 1703936 + 131072;
        float* cx2g    = cf2 + 4096;
        float* partial = cx2g + 53248;

        prep_fused<<<PREP_F_BLOCKS + PREP_X_BLOCKS, 256, 0, stream>>>(
            features, bw, dataset, fh, cf2, xh, cx2g);
        kde_main_fast<<<QTILES * SPLITS, 256, 0, stream>>>(fh, cx2g, xh, partial);
        reduce_kernel<<<QCNT / 256, 256, 0, stream>>>(partial, cf2, norm, out, SPLITS);
    } else {
        _Float16* fh = (_Float16*)ws;                 // 131072 floats
        float* cf2     = ws + 131072;
        float* cx2     = ws + 131072 + 4096;
        float* partial = ws + 131072 + 4096 + 50176;  // FSPLITS*QCNT

        prep_f_kernel<<<QCNT / 4, 256, 0, stream>>>(features, bw, fh, cf2);
        prep_x2_kernel<<<(NCNT + 255) / 256, 256, 0, stream>>>(dataset, cx2);
        dim3 grid(QCNT / 256, FSPLITS);
        kde_main_fb<<<grid, 256, 0, stream>>>(fh, cx2, dataset, partial);
        reduce_kernel<<<QCNT / 256, 256, 0, stream>>>(partial, cf2, norm, out, FSPLITS);
    }
}